// Round 1
// baseline (65.900 us; speedup 1.0000x reference)
//
#include <hip/hip_runtime.h>

// MultiLabelAdaptiveMarginLoss: B=256, C=4096, K=32
// loss = (1/C) * sum_{b,k valid} sum_{j != t} relu(1 + (m_t - m_j) - (x_t - x_j))
// Rewrite: diff = a_k + c_j with a_k = 1 + m_t - x_t, c_j = x_j - m_j.
// j==t term is relu(a_t + c_t) = relu(1) = 1 -> sum over all j, subtract 1
// per valid target (folded into the accumulator init of lanes tid<K).
//
// Structure: one block per row, 1024 threads (16 waves/CU, 4/SIMD for latency
// hiding). No LDS staging of c_j: each element is consumed by exactly one
// thread, so it lives in registers (float4 load -> 32x4 relu terms).
// 4 independent accumulator chains (one per float4 component) keep the fp-add
// dependency chain at 32 instead of 512. Single kernel: per-block partial is
// atomically added to out[0], which is zeroed by a memset node in the graph.

#define BB 256
#define CC 4096
#define KK 32
#define THREADS 1024          // CC/4 float4 elements, one per thread

__global__ __launch_bounds__(THREADS) void mlam_fused(
    const float* __restrict__ input,
    const float* __restrict__ margin,
    const int* __restrict__ target,
    float* __restrict__ out) {

    __shared__ float sa[KK];               // a_k (=-1e30 for padded targets)
    __shared__ float swave[THREADS / 64];  // cross-wave partials

    const int b   = blockIdx.x;
    const int tid = threadIdx.x;
    const float* in_row = input  + (size_t)b * CC;
    const float* mg_row = margin + (size_t)b * CC;

    // Issue the bulk loads first — independent of the target gather below,
    // so their latency overlaps the scattered gather loads.
    const float4 x = ((const float4*)in_row)[tid];
    const float4 m = ((const float4*)mg_row)[tid];

    // Lanes 0..31 gather per-target scalars. A valid target contributes
    // relu(1)=1 at j==t which must be removed: init that lane's acc to -1.
    float acc0 = 0.0f;
    if (tid < KK) {
        const int t = target[b * KK + tid];
        if (t >= 0) {
            sa[tid] = 1.0f + mg_row[t] - in_row[t];
            acc0 = -1.0f;
        } else {
            sa[tid] = -1e30f;   // relu(a+c) == 0 for all j
        }
    }
    __syncthreads();

    // Broadcast a_k into registers (contiguous LDS reads, broadcast = no conflicts).
    float a[KK];
#pragma unroll
    for (int k = 0; k < KK; ++k) a[k] = sa[k];

    const float cx = x.x - m.x;
    const float cy = x.y - m.y;
    const float cz = x.z - m.z;
    const float cw = x.w - m.w;

    // 4 independent accumulator chains, 32 deps each.
    float ax = acc0, ay = 0.0f, az = 0.0f, aw = 0.0f;
#pragma unroll
    for (int k = 0; k < KK; ++k) {
        const float av = a[k];
        ax += fmaxf(av + cx, 0.0f);
        ay += fmaxf(av + cy, 0.0f);
        az += fmaxf(av + cz, 0.0f);
        aw += fmaxf(av + cw, 0.0f);
    }
    float acc = (ax + ay) + (az + aw);

    // Wave64 reduce, then cross-wave via LDS.
#pragma unroll
    for (int off = 32; off > 0; off >>= 1)
        acc += __shfl_down(acc, off, 64);
    if ((tid & 63) == 0) swave[tid >> 6] = acc;
    __syncthreads();

    if (tid == 0) {
        float tot = 0.0f;
#pragma unroll
        for (int w = 0; w < THREADS / 64; ++w) tot += swave[w];
        atomicAdd(out, tot * (1.0f / (float)CC));
    }
}

extern "C" void kernel_launch(void* const* d_in, const int* in_sizes, int n_in,
                              void* d_out, int out_size, void* d_ws, size_t ws_size,
                              hipStream_t stream) {
    const float* input  = (const float*)d_in[0];   // [B, C] fp32
    const float* margin = (const float*)d_in[1];   // [B, C] fp32
    const int*   target = (const int*)d_in[2];     // [B, K] int32
    float* out = (float*)d_out;                    // scalar

    hipMemsetAsync(out, 0, sizeof(float), stream);
    mlam_fused<<<BB, THREADS, 0, stream>>>(input, margin, target, out);
}